// Round 3
// baseline (321.726 us; speedup 1.0000x reference)
//
#include <hip/hip_runtime.h>
#include <hip/hip_bf16.h>

#define NB 8
#define NC 128
#define NN 2048
#define NH 4
#define HD 32
#define NOUT 128
#define QB 16

typedef _Float16 half8 __attribute__((ext_vector_type(8)));
typedef _Float16 half4 __attribute__((ext_vector_type(4)));
typedef float f32x4 __attribute__((ext_vector_type(4)));

__device__ __forceinline__ f32x4 mfma16(half8 a, half8 b, f32x4 c) {
  return __builtin_amdgcn_mfma_f32_16x16x32_f16(a, b, c, 0, 0, 0);
}
__device__ __forceinline__ f32x4 mfma16k16(half4 a, half4 b, f32x4 c) {
  return __builtin_amdgcn_mfma_f32_16x16x16f16(a, b, c, 0, 0, 0);
}

// ---------------- Kernel 0: weight prep (fp32 -> fp16, transposed) ----------------
__global__ __launch_bounds__(256) void k_prep(
    const float* __restrict__ Wq, const float* __restrict__ Wk,
    const float* __restrict__ Wv, const float* __restrict__ Wo,
    _Float16* __restrict__ WqT, _Float16* __restrict__ WkT,
    _Float16* __restrict__ WvT, _Float16* __restrict__ WoT)
{
  int id = blockIdx.x * 256 + threadIdx.x;       // 65536 total
  if (id < 3 * 16384) {
    int m = id >> 14, rem = id & 16383;
    int h = rem >> 12, d = (rem >> 7) & 31, c = rem & 127;
    const float* W = (m == 0) ? Wq : (m == 1) ? Wk : Wv;
    _Float16* WT   = (m == 0) ? WqT : (m == 1) ? WkT : WvT;
    WT[(h * 32 + d) * 128 + c] = (_Float16)W[(h * 128 + c) * 32 + d];
  } else {
    int j = id - 49152;
    int o = j >> 7, c = j & 127;
    WoT[o * 128 + c] = (_Float16)Wo[c * 128 + o];
  }
}

// ---------------- Kernel 1: QKV projections ----------------
__global__ __launch_bounds__(256) void k_proj(
    const float* __restrict__ x, const _Float16* __restrict__ WqT,
    const _Float16* __restrict__ WkT, const _Float16* __restrict__ WvT,
    _Float16* __restrict__ qo, _Float16* __restrict__ ko, _Float16* __restrict__ vto)
{
  __shared__ _Float16 xs[32][136];
  const int bid = blockIdx.x;
  const int b  = bid & 7;
  const int n0 = (bid >> 3) * 32;
  const int tid = threadIdx.x;
  const int h = tid >> 6, l = tid & 63, lr = l & 15, lg = l >> 4;

  {
    int c  = tid >> 1;
    int nq = (tid & 1) * 16;
    const float* src = x + (size_t)(b * NC + c) * NN + n0 + nq;
#pragma unroll
    for (int i = 0; i < 4; ++i) {
      f32x4 v = *(const f32x4*)(src + i * 4);
#pragma unroll
      for (int j = 0; j < 4; ++j) xs[nq + i * 4 + j][c] = (_Float16)v[j];
    }
  }
  __syncthreads();

  half8 a[2][4];
#pragma unroll
  for (int rf = 0; rf < 2; ++rf)
#pragma unroll
    for (int kc = 0; kc < 4; ++kc)
      a[rf][kc] = *(const half8*)(&xs[rf * 16 + lr][kc * 32 + lg * 8]);

#pragma unroll
  for (int m = 0; m < 2; ++m) {
    const _Float16* WT = m ? WkT : WqT;
    _Float16* dst      = m ? ko : qo;
    f32x4 acc[2][2] = {};
#pragma unroll
    for (int kc = 0; kc < 4; ++kc) {
      half8 wb[2];
#pragma unroll
      for (int cf = 0; cf < 2; ++cf)
        wb[cf] = *(const half8*)(WT + (size_t)(h * HD + cf * 16 + lr) * NC + kc * 32 + lg * 8);
#pragma unroll
      for (int rf = 0; rf < 2; ++rf)
#pragma unroll
        for (int cf = 0; cf < 2; ++cf)
          acc[rf][cf] = mfma16(a[rf][kc], wb[cf], acc[rf][cf]);
    }
#pragma unroll
    for (int rf = 0; rf < 2; ++rf)
#pragma unroll
      for (int cf = 0; cf < 2; ++cf)
#pragma unroll
        for (int r = 0; r < 4; ++r)
          dst[((size_t)(b * NH + h) * NN + n0 + rf * 16 + lg * 4 + r) * HD + cf * 16 + lr] =
              (_Float16)acc[rf][cf][r];
  }

  {
    f32x4 acc[2][2] = {};
#pragma unroll
    for (int kc = 0; kc < 4; ++kc) {
      half8 aw[2];
#pragma unroll
      for (int rf = 0; rf < 2; ++rf)
        aw[rf] = *(const half8*)(WvT + (size_t)(h * HD + rf * 16 + lr) * NC + kc * 32 + lg * 8);
#pragma unroll
      for (int rf = 0; rf < 2; ++rf)
#pragma unroll
        for (int nf = 0; nf < 2; ++nf)
          acc[rf][nf] = mfma16(aw[rf], a[nf][kc], acc[rf][nf]);
    }
#pragma unroll
    for (int rf = 0; rf < 2; ++rf)
#pragma unroll
      for (int nf = 0; nf < 2; ++nf)
#pragma unroll
        for (int r = 0; r < 4; ++r)
          vto[((size_t)(b * NH + h) * HD + rf * 16 + lg * 4 + r) * NN + n0 + nf * 16 + lr] =
              (_Float16)acc[rf][nf][r];
  }
}

// ---------------- Kernel 2: attention + adj + W_o (all-heads-per-wave) ----------------
// grid 1024: b = bid&7, n0 = (bid>>3)*16. Wave w owns column tiles ct = w+4t.
// Swapped QK (A=K,B=Q): lane(lr,lg) reg r = S[m=lg*4+r][n=lr] -> p in-register,
// adj head-mean in-register, PV A-frag (16x16x16, k=lg*4+j) = p regs directly.
__global__ __launch_bounds__(256, 4) void k_attn(
    const _Float16* __restrict__ q, const _Float16* __restrict__ k,
    const _Float16* __restrict__ vt, const _Float16* __restrict__ WoT,
    float* __restrict__ outT, float* __restrict__ adj)
{
  __shared__ float r0[4224];          // red[256] | opartA[16*132]@0 + opartB@2112 | ot[128*20]
  __shared__ _Float16 ocat[16 * 136];

  const int bid = blockIdx.x;
  const int b  = bid & 7;
  const int n0 = (bid >> 3) * QB;
  const int w  = threadIdx.x >> 6;
  const int l  = threadIdx.x & 63;
  const int lr = l & 15, lg = l >> 4;

  const size_t hstr = (size_t)NN * HD;   // per-head stride for q,k and vt alike
  const _Float16* kb_base = k  + (size_t)b * NH * hstr;
  const _Float16* vb_base = vt + (size_t)b * NH * hstr;
  const _Float16* qb_base = q  + (size_t)b * NH * hstr;

  half8 qa[NH];
#pragma unroll
  for (int h = 0; h < NH; ++h)
    qa[h] = *(const half8*)(qb_base + h * hstr + (size_t)(n0 + lr) * HD + lg * 8);

  const float c1 = 0.25504527f;   // (1/sqrt(32)) * log2(e)
  const float c2 = 17.3123405f;   // 12 * log2(e)
  const f32x4 z{};

  // ---- Pass 1: row sums ----
  float rs[NH] = {};
  {
    const _Float16* kp = kb_base + (size_t)(w * 16 + lr) * HD + lg * 8;
    for (int t = 0; t < NN / 64; ++t) {
      half8 kb[NH];
#pragma unroll
      for (int h = 0; h < NH; ++h) kb[h] = *(const half8*)(kp + h * hstr);
      f32x4 s[NH];
#pragma unroll
      for (int h = 0; h < NH; ++h) s[h] = mfma16(kb[h], qa[h], z);
#pragma unroll
      for (int h = 0; h < NH; ++h)
        rs[h] += (__builtin_amdgcn_exp2f(s[h][0] * c1 - c2) +
                  __builtin_amdgcn_exp2f(s[h][1] * c1 - c2)) +
                 (__builtin_amdgcn_exp2f(s[h][2] * c1 - c2) +
                  __builtin_amdgcn_exp2f(s[h][3] * c1 - c2));
      kp += 64 * HD;
    }
  }
#pragma unroll
  for (int h = 0; h < NH; ++h) {
    rs[h] += __shfl_xor(rs[h], 16);
    rs[h] += __shfl_xor(rs[h], 32);
  }
  {
    float v = (lg == 0) ? rs[0] : (lg == 1) ? rs[1] : (lg == 2) ? rs[2] : rs[3];
    r0[w * 64 + lg * 16 + lr] = v;
  }
  __syncthreads();
  float ah[NH];
#pragma unroll
  for (int h = 0; h < NH; ++h) {
    float S = r0[h * 16 + lr] + r0[64 + h * 16 + lr] +
              r0[128 + h * 16 + lr] + r0[192 + h * 16 + lr];
    ah[h] = -c2 - __builtin_amdgcn_logf(S);   // log2
  }
  __syncthreads();   // red region dead; r0 will be reused as opart

  // ---- Pass 2: p in-register -> adj + PV ----
  f32x4 oacc[NH][2] = {};
  {
    const _Float16* kp  = kb_base + (size_t)(w * 16 + lr) * HD + lg * 8;
    const _Float16* vp0 = vb_base + (size_t)lr * NN + w * 16 + lg * 4;
    const _Float16* vp1 = vb_base + (size_t)(16 + lr) * NN + w * 16 + lg * 4;
    float* adjp = adj + ((size_t)b * NN + n0 + lr) * NN + w * 16 + lg * 4;
    for (int t = 0; t < NN / 64; ++t) {
      half8 kb[NH];
#pragma unroll
      for (int h = 0; h < NH; ++h) kb[h] = *(const half8*)(kp + h * hstr);
      f32x4 s[NH];
#pragma unroll
      for (int h = 0; h < NH; ++h) s[h] = mfma16(kb[h], qa[h], z);
      // V loads issued early (independent of p)
      half4 vb0[NH], vb1[NH];
#pragma unroll
      for (int h = 0; h < NH; ++h) {
        vb0[h] = *(const half4*)(vp0 + h * hstr);
        vb1[h] = *(const half4*)(vp1 + h * hstr);
      }
      f32x4 adjv{};
      half4 pa[NH];
#pragma unroll
      for (int h = 0; h < NH; ++h) {
        float p0 = __builtin_amdgcn_exp2f(s[h][0] * c1 + ah[h]);
        float p1 = __builtin_amdgcn_exp2f(s[h][1] * c1 + ah[h]);
        float p2 = __builtin_amdgcn_exp2f(s[h][2] * c1 + ah[h]);
        float p3 = __builtin_amdgcn_exp2f(s[h][3] * c1 + ah[h]);
        adjv[0] += p0; adjv[1] += p1; adjv[2] += p2; adjv[3] += p3;
        pa[h] = half4{(_Float16)p0, (_Float16)p1, (_Float16)p2, (_Float16)p3};
      }
#pragma unroll
      for (int h = 0; h < NH; ++h) {
        oacc[h][0] = mfma16k16(pa[h], vb0[h], oacc[h][0]);
        oacc[h][1] = mfma16k16(pa[h], vb1[h], oacc[h][1]);
      }
      f32x4 av = adjv * 0.25f;
      *(f32x4*)adjp = av;
      kp += 64 * HD; vp0 += 64; vp1 += 64; adjp += 64;
    }
  }

  // ---- O cross-wave reduction: waves 0,1 write bufA/bufB; waves 2,3 add ----
  // oacc[h][df] reg r = O[n = lg*4+r][d = h*32 + df*16 + lr]
  {
    float* buf = &r0[(w & 1) * 2112];
    if (w < 2) {
#pragma unroll
      for (int h = 0; h < NH; ++h)
#pragma unroll
        for (int df = 0; df < 2; ++df)
#pragma unroll
          for (int r = 0; r < 4; ++r)
            buf[(lg * 4 + r) * 132 + h * 32 + df * 16 + lr] = oacc[h][df][r];
    }
    __syncthreads();
    if (w >= 2) {
#pragma unroll
      for (int h = 0; h < NH; ++h)
#pragma unroll
        for (int df = 0; df < 2; ++df)
#pragma unroll
          for (int r = 0; r < 4; ++r)
            buf[(lg * 4 + r) * 132 + h * 32 + df * 16 + lr] += oacc[h][df][r];
    }
    __syncthreads();
  }
  // ocat[n][d] fp16 = bufA + bufB
  {
    int n = threadIdx.x >> 4, d8 = (threadIdx.x & 15) * 8;
    half8 hv;
#pragma unroll
    for (int j = 0; j < 8; ++j)
      hv[j] = (_Float16)(r0[n * 132 + d8 + j] + r0[2112 + n * 132 + d8 + j]);
    *(half8*)&ocat[n * 136 + d8] = hv;
  }
  __syncthreads();

  // ---- W_o: wave w computes o-slice [w*32, w*32+32) ----
  f32x4 o2[2] = {};
#pragma unroll
  for (int kc = 0; kc < 4; ++kc) {
    half8 a2 = *(const half8*)&ocat[lr * 136 + kc * 32 + lg * 8];
#pragma unroll
    for (int of = 0; of < 2; ++of) {
      half8 wb = *(const half8*)(WoT + (size_t)(w * 32 + of * 16 + lr) * NOUT + kc * 32 + lg * 8);
      o2[of] = mfma16(a2, wb, o2[of]);
    }
  }
  // transpose via r0 (opart dead; all its reads were before the last barrier)
#pragma unroll
  for (int of = 0; of < 2; ++of)
#pragma unroll
    for (int r = 0; r < 4; ++r)
      r0[(w * 32 + of * 16 + lr) * 20 + lg * 4 + r] = o2[of][r];
  __syncthreads();
  {
    int o  = threadIdx.x >> 1;
    int hf = threadIdx.x & 1;
    float* dst = outT + ((size_t)(b * NOUT) + o) * NN + n0 + hf * 8;
    *(f32x4*)dst       = *(const f32x4*)&r0[o * 20 + hf * 8];
    *(f32x4*)(dst + 4) = *(const f32x4*)&r0[o * 20 + hf * 8 + 4];
  }
}

extern "C" void kernel_launch(void* const* d_in, const int* in_sizes, int n_in,
                              void* d_out, int out_size, void* d_ws, size_t ws_size,
                              hipStream_t stream) {
  const float* x  = (const float*)d_in[0];
  const float* Wq = (const float*)d_in[1];
  const float* Wk = (const float*)d_in[2];
  const float* Wv = (const float*)d_in[3];
  const float* Wo = (const float*)d_in[4];

  float* outT = (float*)d_out;                   // [B,128,N]
  float* adj  = outT + (size_t)NB * NOUT * NN;   // [B,N,N]

  const size_t qkv_elems = (size_t)NB * NH * NN * HD;
  _Float16* qw  = (_Float16*)d_ws;
  _Float16* kw  = qw + qkv_elems;
  _Float16* vw  = kw + qkv_elems;
  _Float16* wqT = vw + qkv_elems;
  _Float16* wkT = wqT + 16384;
  _Float16* wvT = wkT + 16384;
  _Float16* woT = wvT + 16384;

  k_prep<<<dim3(256), dim3(256), 0, stream>>>(Wq, Wk, Wv, Wo, wqT, wkT, wvT, woT);
  k_proj<<<dim3(NB * (NN / 32)), dim3(256), 0, stream>>>(x, wqT, wkT, wvT, qw, kw, vw);
  k_attn<<<dim3(NB * (NN / QB)), dim3(256), 0, stream>>>(qw, kw, vw, woT, outT, adj);
}

// Round 4
// 219.307 us; speedup vs baseline: 1.4670x; 1.4670x over previous
//
#include <hip/hip_runtime.h>
#include <hip/hip_bf16.h>

#define NB 8
#define NC 128
#define NN 2048
#define NH 4
#define HD 32
#define NOUT 128
#define QB 32

typedef _Float16 half8 __attribute__((ext_vector_type(8)));
typedef _Float16 half4 __attribute__((ext_vector_type(4)));
typedef float f32x4 __attribute__((ext_vector_type(4)));

__device__ __forceinline__ f32x4 mfma16(half8 a, half8 b, f32x4 c) {
  return __builtin_amdgcn_mfma_f32_16x16x32_f16(a, b, c, 0, 0, 0);
}
__device__ __forceinline__ f32x4 mfma16k16(half4 a, half4 b, f32x4 c) {
  return __builtin_amdgcn_mfma_f32_16x16x16f16(a, b, c, 0, 0, 0);
}

// ---------------- Kernel 0: weight prep (fp32 -> fp16, transposed) ----------------
__global__ __launch_bounds__(256) void k_prep(
    const float* __restrict__ Wq, const float* __restrict__ Wk,
    const float* __restrict__ Wv, const float* __restrict__ Wo,
    _Float16* __restrict__ WqT, _Float16* __restrict__ WkT,
    _Float16* __restrict__ WvT, _Float16* __restrict__ WoT)
{
  int id = blockIdx.x * 256 + threadIdx.x;       // 65536 total
  if (id < 3 * 16384) {
    int m = id >> 14, rem = id & 16383;
    int h = rem >> 12, d = (rem >> 7) & 31, c = rem & 127;
    const float* W = (m == 0) ? Wq : (m == 1) ? Wk : Wv;
    _Float16* WT   = (m == 0) ? WqT : (m == 1) ? WkT : WvT;
    WT[(h * 32 + d) * 128 + c] = (_Float16)W[(h * 128 + c) * 32 + d];
  } else {
    int j = id - 49152;
    int o = j >> 7, c = j & 127;
    WoT[o * 128 + c] = (_Float16)Wo[c * 128 + o];
  }
}

// ---------------- Kernel 1: QKV projections ----------------
// q,k: [b][h][n][32]; v: [b][h][d][n-INTERLEAVED] (see pos formula; pairs the
// K16 B-fragments of key-groups g and g+4 into one 16B chunk).
__global__ __launch_bounds__(256) void k_proj(
    const float* __restrict__ x, const _Float16* __restrict__ WqT,
    const _Float16* __restrict__ WkT, const _Float16* __restrict__ WvT,
    _Float16* __restrict__ qo, _Float16* __restrict__ ko, _Float16* __restrict__ vto)
{
  __shared__ _Float16 xs[32][136];
  const int bid = blockIdx.x;
  const int b  = bid & 7;
  const int n0 = (bid >> 3) * 32;
  const int tid = threadIdx.x;
  const int h = tid >> 6, l = tid & 63, lr = l & 15, lg = l >> 4;

  {
    int c  = tid >> 1;
    int nq = (tid & 1) * 16;
    const float* src = x + (size_t)(b * NC + c) * NN + n0 + nq;
#pragma unroll
    for (int i = 0; i < 4; ++i) {
      f32x4 v = *(const f32x4*)(src + i * 4);
#pragma unroll
      for (int j = 0; j < 4; ++j) xs[nq + i * 4 + j][c] = (_Float16)v[j];
    }
  }
  __syncthreads();

  half8 a[2][4];
#pragma unroll
  for (int rf = 0; rf < 2; ++rf)
#pragma unroll
    for (int kc = 0; kc < 4; ++kc)
      a[rf][kc] = *(const half8*)(&xs[rf * 16 + lr][kc * 32 + lg * 8]);

#pragma unroll
  for (int m = 0; m < 2; ++m) {
    const _Float16* WT = m ? WkT : WqT;
    _Float16* dst      = m ? ko : qo;
    f32x4 acc[2][2] = {};
#pragma unroll
    for (int kc = 0; kc < 4; ++kc) {
      half8 wb[2];
#pragma unroll
      for (int cf = 0; cf < 2; ++cf)
        wb[cf] = *(const half8*)(WT + (size_t)(h * HD + cf * 16 + lr) * NC + kc * 32 + lg * 8);
#pragma unroll
      for (int rf = 0; rf < 2; ++rf)
#pragma unroll
        for (int cf = 0; cf < 2; ++cf)
          acc[rf][cf] = mfma16(a[rf][kc], wb[cf], acc[rf][cf]);
    }
#pragma unroll
    for (int rf = 0; rf < 2; ++rf)
#pragma unroll
      for (int cf = 0; cf < 2; ++cf)
#pragma unroll
        for (int r = 0; r < 4; ++r)
          dst[((size_t)(b * NH + h) * NN + n0 + rf * 16 + lg * 4 + r) * HD + cf * 16 + lr] =
              (_Float16)acc[rf][cf][r];
  }

  {
    f32x4 acc[2][2] = {};
#pragma unroll
    for (int kc = 0; kc < 4; ++kc) {
      half8 aw[2];
#pragma unroll
      for (int rf = 0; rf < 2; ++rf)
        aw[rf] = *(const half8*)(WvT + (size_t)(h * HD + rf * 16 + lr) * NC + kc * 32 + lg * 8);
#pragma unroll
      for (int rf = 0; rf < 2; ++rf)
#pragma unroll
        for (int nf = 0; nf < 2; ++nf)
          acc[rf][nf] = mfma16(aw[rf], a[nf][kc], acc[rf][nf]);
    }
#pragma unroll
    for (int rf = 0; rf < 2; ++rf)
#pragma unroll
      for (int nf = 0; nf < 2; ++nf) {
        // interleaved store position for key m = n0 + nf*16 + lr
        int g   = (n0 >> 4) + nf;
        int pos = (g >> 3) * 128 + (g & 3) * 32 + (lr >> 2) * 8 +
                  (((g >> 2) & 1) * 4) + (lr & 3);
#pragma unroll
        for (int r = 0; r < 4; ++r)
          vto[((size_t)(b * NH + h) * HD + rf * 16 + lg * 4 + r) * NN + pos] =
              (_Float16)acc[rf][nf][r];
      }
  }
}

// ---------------- Kernel 2: attention + adj + W_o ----------------
// grid 512: b = bid&7, n0 = (bid>>3)*32. 4 waves; wave w owns key strips
// {q16*128 + w*16, q16*128 + 64 + w*16} per 128-key superblock; 2 row-groups.
// Swapped QK: lane(lr,lg) reg r = S[m = base + lg*4 + r][n-row = lr].
__global__ __launch_bounds__(256, 2) void k_attn(
    const _Float16* __restrict__ q, const _Float16* __restrict__ k,
    const _Float16* __restrict__ vt, const _Float16* __restrict__ WoT,
    float* __restrict__ outT, float* __restrict__ adj)
{
  __shared__ __align__(16) char smem[42496];
  float*    red  = (float*)smem;                 // [4][4][2][16]
  float*    opA  = (float*)smem;                 // [32][132]
  float*    opB  = (float*)(smem + 16896);       // [32][132]
  _Float16* ocat = (_Float16*)(smem + 33792);    // [32][136]
  float*    ot   = (float*)smem;                 // [128][36] (aliases opA/opB)

  const int bid = blockIdx.x;
  const int b  = bid & 7;                        // batch == XCD -> K/V L2-resident
  const int n0 = (bid >> 3) * QB;
  const int w  = threadIdx.x >> 6;
  const int l  = threadIdx.x & 63;
  const int lr = l & 15, lg = l >> 4;

  const size_t hstr = (size_t)NN * HD;
  const _Float16* qb = q  + (size_t)b * NH * hstr;
  const _Float16* kb = k  + (size_t)b * NH * hstr;
  const _Float16* vb = vt + (size_t)b * NH * hstr;

  half8 qa[NH][2];
#pragma unroll
  for (int h = 0; h < NH; ++h)
#pragma unroll
    for (int rg = 0; rg < 2; ++rg)
      qa[h][rg] = *(const half8*)(qb + h * hstr + (size_t)(n0 + rg * 16 + lr) * HD + lg * 8);

  const float c1 = 0.25504527f;   // (1/sqrt(32)) * log2(e)
  const float c2 = 17.3123405f;   // 12 * log2(e)
  const f32x4 z{};

  // ---- Pass 1: row sums ----
  float rs[NH][2] = {};
  for (int q16 = 0; q16 < 16; ++q16) {
    const _Float16* kp = kb + (size_t)(q16 * 128 + w * 16 + lr) * HD + lg * 8;
#pragma unroll
    for (int gp = 0; gp < 2; ++gp) {
      half8 kbf[NH];
#pragma unroll
      for (int h = 0; h < NH; ++h) kbf[h] = *(const half8*)(kp + h * hstr + gp * 64 * HD);
      f32x4 s[NH][2];
#pragma unroll
      for (int h = 0; h < NH; ++h)
#pragma unroll
        for (int rg = 0; rg < 2; ++rg)
          s[h][rg] = mfma16(kbf[h], qa[h][rg], z);
#pragma unroll
      for (int h = 0; h < NH; ++h)
#pragma unroll
        for (int rg = 0; rg < 2; ++rg)
          rs[h][rg] += (__builtin_amdgcn_exp2f(s[h][rg][0] * c1 - c2) +
                        __builtin_amdgcn_exp2f(s[h][rg][1] * c1 - c2)) +
                       (__builtin_amdgcn_exp2f(s[h][rg][2] * c1 - c2) +
                        __builtin_amdgcn_exp2f(s[h][rg][3] * c1 - c2));
    }
  }
#pragma unroll
  for (int h = 0; h < NH; ++h)
#pragma unroll
    for (int rg = 0; rg < 2; ++rg) {
      rs[h][rg] += __shfl_xor(rs[h][rg], 16);
      rs[h][rg] += __shfl_xor(rs[h][rg], 32);
    }
  if (lg == 0) {
#pragma unroll
    for (int h = 0; h < NH; ++h)
#pragma unroll
      for (int rg = 0; rg < 2; ++rg)
        red[w * 128 + (h * 2 + rg) * 16 + lr] = rs[h][rg];
  }
  __syncthreads();
  float ah[NH][2];
#pragma unroll
  for (int h = 0; h < NH; ++h)
#pragma unroll
    for (int rg = 0; rg < 2; ++rg) {
      float S = red[(h * 2 + rg) * 16 + lr] + red[128 + (h * 2 + rg) * 16 + lr] +
                red[256 + (h * 2 + rg) * 16 + lr] + red[384 + (h * 2 + rg) * 16 + lr];
      ah[h][rg] = -c2 - __builtin_amdgcn_logf(S);
    }
  __syncthreads();

  // ---- Pass 2: p in-register -> adj + PV ----
  f32x4 oacc[NH][2][2] = {};   // [h][d-half][rg]
  for (int q16 = 0; q16 < 16; ++q16) {
    const _Float16* kp = kb + (size_t)(q16 * 128 + w * 16 + lr) * HD + lg * 8;
    const _Float16* vp = vb + (size_t)lr * NN + q16 * 128 + w * 32 + lg * 8;
    half8 kbf[2][NH];
    half8 vbf[NH][2];
#pragma unroll
    for (int gp = 0; gp < 2; ++gp)
#pragma unroll
      for (int h = 0; h < NH; ++h)
        kbf[gp][h] = *(const half8*)(kp + h * hstr + gp * 64 * HD);
#pragma unroll
    for (int h = 0; h < NH; ++h)
#pragma unroll
      for (int dh = 0; dh < 2; ++dh)
        vbf[h][dh] = *(const half8*)(vp + h * hstr + (size_t)(dh * 16) * NN);

#pragma unroll
    for (int gp = 0; gp < 2; ++gp) {
      f32x4 s[NH][2];
#pragma unroll
      for (int h = 0; h < NH; ++h)
#pragma unroll
        for (int rg = 0; rg < 2; ++rg)
          s[h][rg] = mfma16(kbf[gp][h], qa[h][rg], z);
      half4 pa[NH][2];
      f32x4 adjv[2] = {};
#pragma unroll
      for (int h = 0; h < NH; ++h)
#pragma unroll
        for (int rg = 0; rg < 2; ++rg) {
          float p0 = __builtin_amdgcn_exp2f(s[h][rg][0] * c1 + ah[h][rg]);
          float p1 = __builtin_amdgcn_exp2f(s[h][rg][1] * c1 + ah[h][rg]);
          float p2 = __builtin_amdgcn_exp2f(s[h][rg][2] * c1 + ah[h][rg]);
          float p3 = __builtin_amdgcn_exp2f(s[h][rg][3] * c1 + ah[h][rg]);
          adjv[rg][0] += p0; adjv[rg][1] += p1; adjv[rg][2] += p2; adjv[rg][3] += p3;
          pa[h][rg] = half4{(_Float16)p0, (_Float16)p1, (_Float16)p2, (_Float16)p3};
        }
#pragma unroll
      for (int rg = 0; rg < 2; ++rg) {
        f32x4 av = adjv[rg] * 0.25f;
        *(f32x4*)(adj + ((size_t)b * NN + n0 + rg * 16 + lr) * NN +
                  q16 * 128 + gp * 64 + w * 16 + lg * 4) = av;
      }
#pragma unroll
      for (int h = 0; h < NH; ++h)
#pragma unroll
        for (int dh = 0; dh < 2; ++dh) {
          half4 vhalf = gp ? __builtin_shufflevector(vbf[h][dh], vbf[h][dh], 4, 5, 6, 7)
                           : __builtin_shufflevector(vbf[h][dh], vbf[h][dh], 0, 1, 2, 3);
#pragma unroll
          for (int rg = 0; rg < 2; ++rg)
            oacc[h][dh][rg] = mfma16k16(pa[h][rg], vhalf, oacc[h][dh][rg]);
        }
    }
  }

  // ---- O cross-wave reduction: pairs (0,2)->opA, (1,3)->opB ----
  // oacc[h][dh][rg] reg r = O[n = rg*16 + lg*4 + r][d = h*32 + dh*16 + lr]
  {
    float* buf = (w & 1) ? opB : opA;
    if (w < 2) {
#pragma unroll
      for (int h = 0; h < NH; ++h)
#pragma unroll
        for (int dh = 0; dh < 2; ++dh)
#pragma unroll
          for (int rg = 0; rg < 2; ++rg)
#pragma unroll
            for (int r = 0; r < 4; ++r)
              buf[(rg * 16 + lg * 4 + r) * 132 + h * 32 + dh * 16 + lr] = oacc[h][dh][rg][r];
    }
    __syncthreads();
    if (w >= 2) {
#pragma unroll
      for (int h = 0; h < NH; ++h)
#pragma unroll
        for (int dh = 0; dh < 2; ++dh)
#pragma unroll
          for (int rg = 0; rg < 2; ++rg)
#pragma unroll
            for (int r = 0; r < 4; ++r)
              buf[(rg * 16 + lg * 4 + r) * 132 + h * 32 + dh * 16 + lr] += oacc[h][dh][rg][r];
    }
    __syncthreads();
  }
  // ocat[n][d] fp16 = opA + opB
  {
    int n = threadIdx.x >> 3, d16 = (threadIdx.x & 7) * 16;
    half8 h0, h1;
#pragma unroll
    for (int j = 0; j < 8; ++j) {
      h0[j] = (_Float16)(opA[n * 132 + d16 + j]     + opB[n * 132 + d16 + j]);
      h1[j] = (_Float16)(opA[n * 132 + d16 + 8 + j] + opB[n * 132 + d16 + 8 + j]);
    }
    *(half8*)&ocat[n * 136 + d16]     = h0;
    *(half8*)&ocat[n * 136 + d16 + 8] = h1;
  }
  __syncthreads();

  // ---- W_o: wave w computes o-slice [w*32, w*32+32) for 32 rows ----
  f32x4 o2[2][2] = {};   // [rg][of]
#pragma unroll
  for (int kc = 0; kc < 4; ++kc) {
    half8 a2[2];
#pragma unroll
    for (int rg = 0; rg < 2; ++rg)
      a2[rg] = *(const half8*)&ocat[(rg * 16 + lr) * 136 + kc * 32 + lg * 8];
#pragma unroll
    for (int of = 0; of < 2; ++of) {
      half8 wb = *(const half8*)(WoT + (size_t)(w * 32 + of * 16 + lr) * NOUT + kc * 32 + lg * 8);
#pragma unroll
      for (int rg = 0; rg < 2; ++rg)
        o2[rg][of] = mfma16(a2[rg], wb, o2[rg][of]);
    }
  }
#pragma unroll
  for (int rg = 0; rg < 2; ++rg)
#pragma unroll
    for (int of = 0; of < 2; ++of)
#pragma unroll
      for (int r = 0; r < 4; ++r)
        ot[(w * 32 + of * 16 + lr) * 36 + rg * 16 + lg * 4 + r] = o2[rg][of][r];
  __syncthreads();
  {
    int o   = threadIdx.x >> 1;
    int nh2 = threadIdx.x & 1;
    float* dst = outT + ((size_t)(b * NOUT) + o) * NN + n0 + nh2 * 16;
#pragma unroll
    for (int i = 0; i < 4; ++i)
      *(f32x4*)(dst + i * 4) = *(const f32x4*)&ot[o * 36 + nh2 * 16 + i * 4];
  }
}

extern "C" void kernel_launch(void* const* d_in, const int* in_sizes, int n_in,
                              void* d_out, int out_size, void* d_ws, size_t ws_size,
                              hipStream_t stream) {
  const float* x  = (const float*)d_in[0];
  const float* Wq = (const float*)d_in[1];
  const float* Wk = (const float*)d_in[2];
  const float* Wv = (const float*)d_in[3];
  const float* Wo = (const float*)d_in[4];

  float* outT = (float*)d_out;                   // [B,128,N]
  float* adj  = outT + (size_t)NB * NOUT * NN;   // [B,N,N]

  const size_t qkv_elems = (size_t)NB * NH * NN * HD;
  _Float16* qw  = (_Float16*)d_ws;
  _Float16* kw  = qw + qkv_elems;
  _Float16* vw  = kw + qkv_elems;
  _Float16* wqT = vw + qkv_elems;
  _Float16* wkT = wqT + 16384;
  _Float16* wvT = wkT + 16384;
  _Float16* woT = wvT + 16384;

  k_prep<<<dim3(256), dim3(256), 0, stream>>>(Wq, Wk, Wv, Wo, wqT, wkT, wvT, woT);
  k_proj<<<dim3(NB * (NN / 32)), dim3(256), 0, stream>>>(x, wqT, wkT, wvT, qw, kw, vw);
  k_attn<<<dim3(NB * (NN / QB)), dim3(256), 0, stream>>>(qw, kw, vw, woT, outT, adj);
}